// Round 1
// baseline (28094.730 us; speedup 1.0000x reference)
//
#include <hip/hip_runtime.h>
#include <math.h>

#define BB 32
#define HH 1024
#define EE 512
#define TT 63      // T-1
#define SS 64
#define VV 32000

// ---------------------------------------------------------------------------
// init: copy h0/c0 into state buffer 0, zero the t=0 "prev output" buffer
__global__ __launch_bounds__(256)
void init_kernel(const float* __restrict__ h0, const float* __restrict__ c0,
                 float* __restrict__ h_state, float* __restrict__ c_state,
                 float* __restrict__ prev0)
{
    int i = blockIdx.x * 256 + threadIdx.x;
    if (i < 2 * BB * HH) { h_state[i] = h0[i]; c_state[i] = c0[i]; }
    if (i < BB * HH) prev0[i] = 0.f;
}

// ---------------------------------------------------------------------------
// embedding gather: xs[t][b][:] = emb[x[b][t]][:]   (time-major for the scan)
__global__ __launch_bounds__(128)
void embed_kernel(const int* __restrict__ x, const float* __restrict__ emb,
                  float* __restrict__ xs)
{
    int t = blockIdx.x >> 5;
    int b = blockIdx.x & 31;
    int tok = x[b * 64 + t];                 // x is [B,64]
    const float4* src = (const float4*)(emb + (size_t)tok * EE);
    float4* dst = (float4*)(xs + ((size_t)t * BB + b) * EE);
    dst[threadIdx.x] = src[threadIdx.x];     // 512 floats = 128 float4
}

// ---------------------------------------------------------------------------
// LSTM cell step. gates = src0@Wih[:, :K0]^T + src1@Wih[:, K0:]^T + h_prev@Whh^T
// + bih + bhh ; torch gate order i,f,g,o in the 4H rows.
// Thread = one (b,h) pair owning all 4 gate accumulators.
// Grid 128 blocks x 256 thr: block covers 8 h x 32 b.
__global__ __launch_bounds__(256)
void lstm_step_kernel(const float* __restrict__ src0, int K0,
                      const float* __restrict__ src1, int K1,
                      const float* __restrict__ Wih, const float* __restrict__ Whh,
                      const float* __restrict__ bih, const float* __restrict__ bhh,
                      const float* __restrict__ h_prev, const float* __restrict__ c_prev,
                      float* __restrict__ h_new, float* __restrict__ c_new)
{
    __shared__ float lds[64 * 33];          // [k][b], pitch 33 kills bank conflicts
    const int tid  = threadIdx.x;
    const int b    = tid & 31;
    const int hl   = tid >> 5;
    const int h    = blockIdx.x * 8 + hl;
    const int lane = tid & 63;
    const int wv   = tid >> 6;
    const int KW   = K0 + K1;               // Wih row length
    const int Ktot = KW + HH;

    float acc0 = 0.f, acc1 = 0.f, acc2 = 0.f, acc3 = 0.f;

    for (int k0 = 0; k0 < Ktot; k0 += 64) {
        // ---- stage 64-k chunk of the (virtual concat) input, all 32 batches
        const float* s; int koff; int stride;
        if (k0 < K0)      { s = src0;   koff = k0;        stride = K0; }
        else if (k0 < KW) { s = src1;   koff = k0 - K0;   stride = K1; }
        else              { s = h_prev; koff = k0 - KW;   stride = HH; }
        #pragma unroll
        for (int r = 0; r < 8; ++r) {
            int bb = wv * 8 + r;
            lds[lane * 33 + bb] = s[(size_t)bb * stride + koff + lane];
        }
        __syncthreads();

        // ---- weight row pointers for this chunk (broadcast across 32 b-lanes)
        const float *wi, *wf, *wg, *wo;
        if (k0 < KW) {
            wi = Wih + (size_t)h            * KW + k0;
            wf = Wih + (size_t)(HH   + h)   * KW + k0;
            wg = Wih + (size_t)(2*HH + h)   * KW + k0;
            wo = Wih + (size_t)(3*HH + h)   * KW + k0;
        } else {
            int c = k0 - KW;
            wi = Whh + (size_t)h            * HH + c;
            wf = Whh + (size_t)(HH   + h)   * HH + c;
            wg = Whh + (size_t)(2*HH + h)   * HH + c;
            wo = Whh + (size_t)(3*HH + h)   * HH + c;
        }
        #pragma unroll
        for (int k = 0; k < 64; k += 4) {
            float4 vi = *(const float4*)(wi + k);
            float4 vf = *(const float4*)(wf + k);
            float4 vg = *(const float4*)(wg + k);
            float4 vo = *(const float4*)(wo + k);
            float x0 = lds[(k+0)*33 + b];
            float x1 = lds[(k+1)*33 + b];
            float x2 = lds[(k+2)*33 + b];
            float x3 = lds[(k+3)*33 + b];
            acc0 = fmaf(x0, vi.x, acc0); acc0 = fmaf(x1, vi.y, acc0);
            acc0 = fmaf(x2, vi.z, acc0); acc0 = fmaf(x3, vi.w, acc0);
            acc1 = fmaf(x0, vf.x, acc1); acc1 = fmaf(x1, vf.y, acc1);
            acc1 = fmaf(x2, vf.z, acc1); acc1 = fmaf(x3, vf.w, acc1);
            acc2 = fmaf(x0, vg.x, acc2); acc2 = fmaf(x1, vg.y, acc2);
            acc2 = fmaf(x2, vg.z, acc2); acc2 = fmaf(x3, vg.w, acc2);
            acc3 = fmaf(x0, vo.x, acc3); acc3 = fmaf(x1, vo.y, acc3);
            acc3 = fmaf(x2, vo.z, acc3); acc3 = fmaf(x3, vo.w, acc3);
        }
        __syncthreads();
    }

    float gi = acc0 + bih[h]        + bhh[h];
    float gf = acc1 + bih[HH + h]   + bhh[HH + h];
    float gg = acc2 + bih[2*HH + h] + bhh[2*HH + h];
    float go = acc3 + bih[3*HH + h] + bhh[3*HH + h];
    float si = 1.f / (1.f + expf(-gi));
    float sf = 1.f / (1.f + expf(-gf));
    float so = 1.f / (1.f + expf(-go));
    float cp = c_prev[(size_t)b * HH + h];
    float cn = sf * cp + si * tanhf(gg);
    float hn = so * tanhf(cn);
    h_new[(size_t)b * HH + h] = hn;
    c_new[(size_t)b * HH + h] = cn;
}

// ---------------------------------------------------------------------------
// out[b][n] = act( (src0|src1 concat) @ W[n,:]^T + bias[n] ), act: 0=none 1=tanh
__global__ __launch_bounds__(256)
void linear_kernel(const float* __restrict__ src0, int K0,
                   const float* __restrict__ src1, int K1,
                   const float* __restrict__ W, const float* __restrict__ bias,
                   float* __restrict__ out, int N, int act)
{
    __shared__ float lds[64 * 33];
    const int tid  = threadIdx.x;
    const int b    = tid & 31;
    const int nl   = tid >> 5;
    const int n    = blockIdx.x * 8 + nl;
    const int lane = tid & 63;
    const int wv   = tid >> 6;
    const int K    = K0 + K1;
    float acc = 0.f;
    const float* wr = W + (size_t)n * K;
    for (int k0 = 0; k0 < K; k0 += 64) {
        const float* s; int koff; int stride;
        if (k0 < K0) { s = src0; koff = k0;      stride = K0; }
        else         { s = src1; koff = k0 - K0; stride = K1; }
        #pragma unroll
        for (int r = 0; r < 8; ++r) {
            int bb = wv * 8 + r;
            lds[lane * 33 + bb] = s[(size_t)bb * stride + koff + lane];
        }
        __syncthreads();
        #pragma unroll
        for (int k = 0; k < 64; k += 4) {
            float4 w4 = *(const float4*)(wr + k0 + k);
            acc = fmaf(lds[(k+0)*33 + b], w4.x, acc);
            acc = fmaf(lds[(k+1)*33 + b], w4.y, acc);
            acc = fmaf(lds[(k+2)*33 + b], w4.z, acc);
            acc = fmaf(lds[(k+3)*33 + b], w4.w, acc);
        }
        __syncthreads();
    }
    float r = acc + bias[n];
    if (act) r = tanhf(r);
    out[(size_t)b * N + n] = r;
}

// ---------------------------------------------------------------------------
// attention tail: s[j] = za[b].x_enc[b][j], softmax_j, ctx = sum_j w_j x_enc[b][j]
// one block per batch
__global__ __launch_bounds__(256)
void attn_kernel(const float* __restrict__ za, const float* __restrict__ x_enc,
                 float* __restrict__ ctx)
{
    __shared__ float zs[HH];
    __shared__ float pp[256];
    __shared__ float wgt[SS];
    const int tid = threadIdx.x;
    const int b = blockIdx.x;
    for (int i = tid; i < HH; i += 256) zs[i] = za[(size_t)b * HH + i];
    __syncthreads();
    // scores: 4 partial dots per j
    int j = tid >> 2, part = tid & 3;
    const float* xe = x_enc + ((size_t)b * SS + j) * HH + part * 256;
    const float* zp = zs + part * 256;
    float p = 0.f;
    for (int k = 0; k < 256; ++k) p = fmaf(zp[k], xe[k], p);
    pp[tid] = p;
    __syncthreads();
    if (tid < SS) {
        float sc = pp[tid*4] + pp[tid*4+1] + pp[tid*4+2] + pp[tid*4+3];
        float m = sc;
        for (int off = 32; off; off >>= 1) m = fmaxf(m, __shfl_xor(m, off));
        float e = expf(sc - m);
        float ssum = e;
        for (int off = 32; off; off >>= 1) ssum += __shfl_xor(ssum, off);
        wgt[tid] = e / ssum;
    }
    __syncthreads();
    for (int k = tid; k < HH; k += 256) {
        float a = 0.f;
        const float* xb = x_enc + (size_t)b * SS * HH + k;
        #pragma unroll 8
        for (int jj = 0; jj < SS; ++jj) a = fmaf(wgt[jj], xb[(size_t)jj * HH], a);
        ctx[(size_t)b * HH + k] = a;
    }
}

// ---------------------------------------------------------------------------
// generator GEMM: out[r][v] = outs_row(r) . Wg[v] + bg[v]
// A row r = b*63+t lives at outs[(t*32+b)*1024]. Tiles: 32 rows x 64 cols,
// K-chunk 64, register tile 2x4 per thread (256 thr).
__global__ __launch_bounds__(256)
void gen_gemm_kernel(const float* __restrict__ outs, const float* __restrict__ Wg,
                     const float* __restrict__ bg, float* __restrict__ out)
{
    __shared__ float As[32 * 68];   // pitch 68: 16B-aligned float4 rows
    __shared__ float Bs[64 * 68];
    const int tid = threadIdx.x;
    const int tn = tid & 15, tm = tid >> 4;
    const int vbase = blockIdx.x * 64;
    const int rbase = blockIdx.y * 32;
    float acc[2][4] = {};

    const int arow = tid >> 3;            // 0..31
    const int acol = (tid & 7) * 8;       // 8 floats per thread
    int rg = rbase + arow;
    int ab = rg / TT, at = rg % TT;
    const float* asrc = outs + ((size_t)at * BB + ab) * HH + acol;
    const int brow = tid >> 2;            // 0..63
    const int bcol = (tid & 3) * 16;      // 16 floats per thread
    const float* bsrc = Wg + (size_t)(vbase + brow) * HH + bcol;

    for (int k0 = 0; k0 < HH; k0 += 64) {
        float4 a4a = *(const float4*)(asrc + k0);
        float4 a4b = *(const float4*)(asrc + k0 + 4);
        *(float4*)&As[arow*68 + acol]     = a4a;
        *(float4*)&As[arow*68 + acol + 4] = a4b;
        float4 q0 = *(const float4*)(bsrc + k0);
        float4 q1 = *(const float4*)(bsrc + k0 + 4);
        float4 q2 = *(const float4*)(bsrc + k0 + 8);
        float4 q3 = *(const float4*)(bsrc + k0 + 12);
        *(float4*)&Bs[brow*68 + bcol]      = q0;
        *(float4*)&Bs[brow*68 + bcol + 4]  = q1;
        *(float4*)&Bs[brow*68 + bcol + 8]  = q2;
        *(float4*)&Bs[brow*68 + bcol + 12] = q3;
        __syncthreads();
        #pragma unroll
        for (int k = 0; k < 64; k += 4) {
            float4 a0 = *(const float4*)&As[(tm*2+0)*68 + k];
            float4 a1 = *(const float4*)&As[(tm*2+1)*68 + k];
            float4 b0 = *(const float4*)&Bs[(tn*4+0)*68 + k];
            float4 b1 = *(const float4*)&Bs[(tn*4+1)*68 + k];
            float4 b2 = *(const float4*)&Bs[(tn*4+2)*68 + k];
            float4 b3 = *(const float4*)&Bs[(tn*4+3)*68 + k];
            acc[0][0] += a0.x*b0.x + a0.y*b0.y + a0.z*b0.z + a0.w*b0.w;
            acc[0][1] += a0.x*b1.x + a0.y*b1.y + a0.z*b1.z + a0.w*b1.w;
            acc[0][2] += a0.x*b2.x + a0.y*b2.y + a0.z*b2.z + a0.w*b2.w;
            acc[0][3] += a0.x*b3.x + a0.y*b3.y + a0.z*b3.z + a0.w*b3.w;
            acc[1][0] += a1.x*b0.x + a1.y*b0.y + a1.z*b0.z + a1.w*b0.w;
            acc[1][1] += a1.x*b1.x + a1.y*b1.y + a1.z*b1.z + a1.w*b1.w;
            acc[1][2] += a1.x*b2.x + a1.y*b2.y + a1.z*b2.z + a1.w*b2.w;
            acc[1][3] += a1.x*b3.x + a1.y*b3.y + a1.z*b3.z + a1.w*b3.w;
        }
        __syncthreads();
    }
    #pragma unroll
    for (int i = 0; i < 2; ++i) {
        int r = rbase + tm*2 + i;
        #pragma unroll
        for (int jj = 0; jj < 4; ++jj) {
            int v = vbase + tn*4 + jj;
            out[(size_t)r * VV + v] = acc[i][jj] + bg[v];
        }
    }
}

// ---------------------------------------------------------------------------
// in-place log_softmax per row of [2016, 32000]
__global__ __launch_bounds__(256)
void logsoftmax_kernel(float* __restrict__ out)
{
    __shared__ float red[4];
    __shared__ float red2[4];
    const int tid = threadIdx.x;
    float* row = out + (size_t)blockIdx.x * VV;
    float m = -1e30f;
    for (int i = tid; i < VV; i += 256) m = fmaxf(m, row[i]);
    for (int off = 32; off; off >>= 1) m = fmaxf(m, __shfl_xor(m, off));
    if ((tid & 63) == 0) red[tid >> 6] = m;
    __syncthreads();
    m = fmaxf(fmaxf(red[0], red[1]), fmaxf(red[2], red[3]));
    float s = 0.f;
    for (int i = tid; i < VV; i += 256) s += expf(row[i] - m);
    for (int off = 32; off; off >>= 1) s += __shfl_xor(s, off);
    if ((tid & 63) == 0) red2[tid >> 6] = s;
    __syncthreads();
    s = red2[0] + red2[1] + red2[2] + red2[3];
    float lse = m + logf(s);
    for (int i = tid; i < VV; i += 256) row[i] = row[i] - lse;
}

// ---------------------------------------------------------------------------
extern "C" void kernel_launch(void* const* d_in, const int* in_sizes, int n_in,
                              void* d_out, int out_size, void* d_ws, size_t ws_size,
                              hipStream_t stream)
{
    (void)in_sizes; (void)n_in; (void)out_size; (void)ws_size;
    const int*   x    = (const int*)  d_in[0];
    const float* h0   = (const float*)d_in[1];
    const float* c0   = (const float*)d_in[2];
    const float* x_enc= (const float*)d_in[3];
    const float* emb  = (const float*)d_in[4];
    const float* Wih0 = (const float*)d_in[5];
    const float* Whh0 = (const float*)d_in[6];
    const float* bih0 = (const float*)d_in[7];
    const float* bhh0 = (const float*)d_in[8];
    const float* Wih1 = (const float*)d_in[9];
    const float* Whh1 = (const float*)d_in[10];
    const float* bih1 = (const float*)d_in[11];
    const float* bhh1 = (const float*)d_in[12];
    const float* Wa   = (const float*)d_in[13];
    const float* ba   = (const float*)d_in[14];
    const float* Wl   = (const float*)d_in[15];
    const float* bl   = (const float*)d_in[16];
    const float* Wg   = (const float*)d_in[17];
    const float* bg   = (const float*)d_in[18];
    float* out = (float*)d_out;

    // workspace layout (floats)
    float* ws      = (float*)d_ws;
    float* h_state = ws;                         // 2 bufs x 2 layers x 32 x 1024
    float* c_state = h_state + 131072;
    float* prev0   = c_state + 131072;           // 32768 zeros
    float* za      = prev0   + 32768;            // 32 x 1024
    float* ctx     = za      + 32768;            // 32 x 1024
    float* xs      = ctx     + 32768;            // [63][32][512]
    float* outs    = xs      + (size_t)TT * BB * EE;  // [63][32][1024]

    init_kernel<<<256, 256, 0, stream>>>(h0, c0, h_state, c_state, prev0);
    embed_kernel<<<TT * BB, 128, 0, stream>>>(x, emb, xs);

    for (int t = 0; t < TT; ++t) {
        const float* e_t  = xs + (size_t)t * BB * EE;
        const float* prev = (t == 0) ? prev0 : (outs + (size_t)(t - 1) * BB * HH);
        float* hc = h_state + (size_t)(t & 1) * 65536;
        float* hn = h_state + (size_t)((t + 1) & 1) * 65536;
        float* cc = c_state + (size_t)(t & 1) * 65536;
        float* cn = c_state + (size_t)((t + 1) & 1) * 65536;
        // layer 0: input = concat(e_t, prev)
        lstm_step_kernel<<<128, 256, 0, stream>>>(e_t, EE, prev, HH,
            Wih0, Whh0, bih0, bhh0, hc, cc, hn, cn);
        // layer 1: input = h0_new
        lstm_step_kernel<<<128, 256, 0, stream>>>(hn, HH, nullptr, 0,
            Wih1, Whh1, bih1, bhh1, hc + 32768, cc + 32768, hn + 32768, cn + 32768);
        // za = z @ Wa^T + ba
        linear_kernel<<<128, 256, 0, stream>>>(hn + 32768, HH, nullptr, 0,
            Wa, ba, za, HH, 0);
        // softmax attention over x_enc
        attn_kernel<<<BB, 256, 0, stream>>>(za, x_enc, ctx);
        // out_t = tanh(concat(z, ctx) @ Wl^T + bl)
        linear_kernel<<<128, 256, 0, stream>>>(hn + 32768, HH, ctx, HH,
            Wl, bl, outs + (size_t)t * BB * HH, HH, 1);
    }

    gen_gemm_kernel<<<dim3(VV / 64, 2016 / 32), 256, 0, stream>>>(outs, Wg, bg, out);
    logsoftmax_kernel<<<2016, 256, 0, stream>>>(out);
}